// Round 2
// baseline (165.796 us; speedup 1.0000x reference)
//
#include <hip/hip_runtime.h>
#include <math.h>

// Problem constants (reference setup_inputs: B=32, H=80, W=120, A=9)
#define NA     9
#define HH     80
#define WWID   120
#define HWSZ   (HH * WWID)        // 9600
#define NANC   (HWSZ * NA)        // 86400 anchors per image
#define NANC4  (NANC / 4)         // 21600 float4 groups
#define PRE_NMS 100
#define NMS_THRESH 0.3f
#define MIN_SIZE 8.0f
#define STRIDE_F 16.0f
#define NBIN   4096               // 12-bit histogram of ordered-f32
#define CAP    2048               // per-batch candidate cap (expected ~183)

// Anchor geometry: all 9 anchors share center (8,8); widths/heights below are
// exact (verified against _generate_anchors(16,(0.5,1,2),(8,16,32))).
__constant__ float c_aw[NA] = {184.f, 368.f, 736.f, 128.f, 256.f, 512.f,  88.f, 176.f, 352.f};
__constant__ float c_ah[NA] = { 96.f, 192.f, 384.f, 128.f, 256.f, 512.f, 176.f, 352.f, 704.f};

// ---------------------------------------------------------------- decode ----
__device__ inline void decode_box(int n, float4 d, float imgW, float imgH,
                                  float& x1, float& y1, float& x2, float& y2) {
    int a = n % NA;
    int s = n / NA;
    int yy = s / WWID;
    int xx = s - yy * WWID;
    float aw = c_aw[a], ah = c_ah[a];
    float acx = 8.0f + STRIDE_F * (float)xx;
    float acy = 8.0f + STRIDE_F * (float)yy;
    float pcx = d.x * aw + acx;
    float pcy = d.y * ah + acy;
    float pw  = expf(d.z) * aw;
    float ph  = expf(d.w) * ah;
    x1 = pcx - 0.5f * pw;
    y1 = pcy - 0.5f * ph;
    x2 = pcx + 0.5f * pw;
    y2 = pcy + 0.5f * ph;
    float mx = imgW - 1.0f, my = imgH - 1.0f;
    x1 = fminf(fmaxf(x1, 0.0f), mx);
    x2 = fminf(fmaxf(x2, 0.0f), mx);
    y1 = fminf(fmaxf(y1, 0.0f), my);
    y2 = fminf(fmaxf(y2, 0.0f), my);
}

// order-preserving uint mapping (monotonic for all floats incl +-inf)
__device__ inline unsigned int f32_ord(float v) {
    unsigned int u = __float_as_uint(v);
    return (u & 0x80000000u) ? ~u : (u | 0x80000000u);
}
__device__ inline float ord_f32(unsigned int ov) {
    unsigned int u = (ov & 0x80000000u) ? (ov ^ 0x80000000u) : ~ov;
    return __uint_as_float(u);
}

// -------------------------------------------------- K0: batch-0 size mask ---
// mask stored in score-memory order m = a*HWSZ + s so K1/K2 reads coalesce.
__global__ void k_mask(const float* __restrict__ delta,
                       const float* __restrict__ img,
                       unsigned char* __restrict__ mask) {
    int n = blockIdx.x * blockDim.x + threadIdx.x;
    if (n >= NANC) return;
    float4 d = reinterpret_cast<const float4*>(delta)[n];  // batch 0, contiguous
    float imgH = img[0], imgW = img[1];
    float x1, y1, x2, y2;
    decode_box(n, d, imgW, imgH, x1, y1, x2, y2);
    float ws = x2 - x1 + 1.0f;
    float hs = y2 - y1 + 1.0f;
    int a = n % NA;
    int s = n / NA;
    mask[a * HWSZ + s] = (ws >= MIN_SIZE && hs >= MIN_SIZE) ? 1 : 0;
}

// --------------------- K1: per-batch 12-bit histogram -> threshold bin T ----
// T[b] = max bin with count(bin' >= T) >= 100  => global top-100 all have
// bin >= T.  Also zeroes the candidate counter for K2.
__global__ __launch_bounds__(1024)
void k_select(const float* __restrict__ score,
              const unsigned char* __restrict__ mask,
              unsigned int* __restrict__ tArr,
              unsigned int* __restrict__ cntArr) {
    __shared__ unsigned int lhist[NBIN];
    __shared__ unsigned int part[1024];
    __shared__ int best;
    int b = blockIdx.x, tid = threadIdx.x;

    for (int i = tid; i < NBIN; i += 1024) lhist[i] = 0;
    if (tid == 0) best = -1;
    __syncthreads();

    const float4* fg = reinterpret_cast<const float4*>(
        score + (size_t)b * (2 * NA * HWSZ) + (size_t)NA * HWSZ);
    const uchar4* mk = reinterpret_cast<const uchar4*>(mask);
    for (int it = 0; it < 22; ++it) {
        int q = it * 1024 + tid;
        if (q < NANC4) {
            float4 v = fg[q];
            uchar4 m = mk[q];
            float a0 = m.x ? v.x : -INFINITY;
            float a1 = m.y ? v.y : -INFINITY;
            float a2 = m.z ? v.z : -INFINITY;
            float a3 = m.w ? v.w : -INFINITY;
            atomicAdd(&lhist[f32_ord(a0) >> 20], 1u);
            atomicAdd(&lhist[f32_ord(a1) >> 20], 1u);
            atomicAdd(&lhist[f32_ord(a2) >> 20], 1u);
            atomicAdd(&lhist[f32_ord(a3) >> 20], 1u);
        }
    }
    __syncthreads();

    // suffix-sum over 1024 groups of 4 bins
    unsigned g0 = lhist[4 * tid + 0], g1 = lhist[4 * tid + 1];
    unsigned g2 = lhist[4 * tid + 2], g3 = lhist[4 * tid + 3];
    part[tid] = g0 + g1 + g2 + g3;
    __syncthreads();
    for (int off = 1; off < 1024; off <<= 1) {
        unsigned v = (tid + off < 1024) ? part[tid + off] : 0u;
        __syncthreads();
        part[tid] += v;
        __syncthreads();
    }
    unsigned above = (tid + 1 < 1024) ? part[tid + 1] : 0u;
    unsigned c3 = above + g3;
    unsigned c2 = c3 + g2;
    unsigned c1 = c2 + g1;
    unsigned c0 = c1 + g0;
    int loc = -1;
    if      (c3 >= PRE_NMS) loc = 4 * tid + 3;
    else if (c2 >= PRE_NMS) loc = 4 * tid + 2;
    else if (c1 >= PRE_NMS) loc = 4 * tid + 1;
    else if (c0 >= PRE_NMS) loc = 4 * tid + 0;
    if (loc >= 0) atomicMax(&best, loc);
    __syncthreads();
    if (tid == 0) { tArr[b] = (unsigned)best; cntArr[b] = 0u; }
}

// ---------------- K2: compact all elements with bin >= T into candidates ----
__global__ __launch_bounds__(256)
void k_compact(const float* __restrict__ score,
               const unsigned char* __restrict__ mask,
               const unsigned int* __restrict__ tArr,
               unsigned int* __restrict__ cntArr,
               unsigned long long* __restrict__ cand) {
    int chunk = blockIdx.x, b = blockIdx.y, tid = threadIdx.x;
    unsigned T = tArr[b];
    const float4* fg = reinterpret_cast<const float4*>(
        score + (size_t)b * (2 * NA * HWSZ) + (size_t)NA * HWSZ);
    const uchar4* mk = reinterpret_cast<const uchar4*>(mask);
    for (int it = 0; it < 4; ++it) {
        int q = chunk * 1024 + it * 256 + tid;
        if (q >= NANC4) continue;
        float4 v = mk ? fg[q] : fg[q];
        uchar4 m = mk[q];
        float av[4] = { m.x ? v.x : -INFINITY, m.y ? v.y : -INFINITY,
                        m.z ? v.z : -INFINITY, m.w ? v.w : -INFINITY };
        #pragma unroll
        for (int c = 0; c < 4; ++c) {
            unsigned ov = f32_ord(av[c]);
            if ((ov >> 20) >= T) {
                int mfull = 4 * q + c;              // memory order a*HWSZ + s
                int a = mfull / HWSZ;
                int s = mfull - a * HWSZ;
                unsigned n = (unsigned)(s * NA + a); // anchor order (top_k index)
                unsigned slot = atomicAdd(&cntArr[b], 1u);
                if (slot < CAP)
                    cand[(size_t)b * CAP + slot] =
                        ((unsigned long long)ov << 32) |
                        (unsigned long long)(0xFFFFFFFFu - n);  // low idx wins ties
            }
        }
    }
}

// generic in-LDS bitonic sort, descending, S = power of 2 (block-uniform)
__device__ inline void bitonic_desc(unsigned long long* sh, int S) {
    for (int k = 2; k <= S; k <<= 1) {
        for (int j = k >> 1; j > 0; j >>= 1) {
            for (int i = threadIdx.x; i < S; i += 1024) {
                int ix = i ^ j;
                if (ix > i) {
                    unsigned long long va = sh[i], vb = sh[ix];
                    bool up = ((i & k) == 0);
                    bool sw = up ? (va < vb) : (va > vb);
                    if (sw) { sh[i] = vb; sh[ix] = va; }
                }
            }
            __syncthreads();
        }
    }
}

// --------- K3: per-batch sort candidates, decode top-100, NMS, write -------
__global__ __launch_bounds__(1024)
void k_final(const unsigned long long* __restrict__ cand,
             const unsigned int* __restrict__ cntArr,
             const float* __restrict__ delta,
             const float* __restrict__ img,
             float* __restrict__ out) {
    __shared__ unsigned long long sh[CAP];
    __shared__ float bx1[PRE_NMS], by1[PRE_NMS], bx2[PRE_NMS], by2[PRE_NMS];
    __shared__ float bsc[PRE_NMS], barea[PRE_NMS];
    __shared__ unsigned int supW[PRE_NMS * 4];   // suppress bit-matrix rows
    __shared__ unsigned int keepW[4];
    __shared__ int osrc[PRE_NMS];

    int b = blockIdx.x, tid = threadIdx.x;
    int nc = min((int)cntArr[b], CAP);
    int S = 128;
    while (S < nc) S <<= 1;

    for (int l = tid; l < S; l += 1024)
        sh[l] = (l < nc) ? cand[(size_t)b * CAP + l] : 0ull;
    if (tid < 4) keepW[tid] = 0u;
    if (tid < PRE_NMS * 4) supW[tid] = 0u;
    __syncthreads();

    bitonic_desc(sh, S);   // ends with __syncthreads

    float imgH = img[0], imgW = img[1];
    if (tid < PRE_NMS) {
        unsigned long long key = sh[tid];
        float x1 = 0.f, y1 = 0.f, x2 = 0.f, y2 = 0.f, v = -INFINITY, ar = 1.f;
        if (key != 0ull) {   // real candidate (pad keys are exactly 0)
            unsigned n = 0xFFFFFFFFu - (unsigned)(key & 0xFFFFFFFFu);
            v = ord_f32((unsigned)(key >> 32));
            // delta.reshape(B,-1,4): row n = flat elems [4n..4n+3] (contiguous)
            float4 d = reinterpret_cast<const float4*>(
                delta + (size_t)b * (4 * NANC))[n];
            decode_box((int)n, d, imgW, imgH, x1, y1, x2, y2);
            ar = (x2 - x1 + 1.0f) * (y2 - y1 + 1.0f);
        }
        bx1[tid] = x1; by1[tid] = y1; bx2[tid] = x2; by2[tid] = y2;
        bsc[tid] = v;  barea[tid] = ar;
        if (key != 0ull && isfinite(v))
            atomicOr(&keepW[tid >> 5], 1u << (tid & 31));
    }
    __syncthreads();

    // 100x100 suppress matrix: bit j of row i set iff j>i and IoU>thresh
    for (int p = tid; p < PRE_NMS * PRE_NMS; p += 1024) {
        int i = p / PRE_NMS;
        int j = p - i * PRE_NMS;
        if (j > i) {
            float ix1 = fmaxf(bx1[i], bx1[j]);
            float iy1 = fmaxf(by1[i], by1[j]);
            float ix2 = fminf(bx2[i], bx2[j]);
            float iy2 = fminf(by2[i], by2[j]);
            float iw = fmaxf(ix2 - ix1 + 1.0f, 0.0f);
            float ih = fmaxf(iy2 - iy1 + 1.0f, 0.0f);
            float inter = iw * ih;
            float iou = inter / (barea[i] + barea[j] - inter);
            if (iou > NMS_THRESH)
                atomicOr(&supW[i * 4 + (j >> 5)], 1u << (j & 31));
        }
    }
    __syncthreads();

    // greedy pass entirely in wave-0 registers (no barriers)
    if (tid < 64) {
        unsigned r0w0 = supW[tid * 4 + 0], r0w1 = supW[tid * 4 + 1];
        unsigned r0w2 = supW[tid * 4 + 2], r0w3 = supW[tid * 4 + 3];
        unsigned r1w0 = 0, r1w1 = 0, r1w2 = 0, r1w3 = 0;
        if (tid < PRE_NMS - 64) {
            r1w0 = supW[(64 + tid) * 4 + 0]; r1w1 = supW[(64 + tid) * 4 + 1];
            r1w2 = supW[(64 + tid) * 4 + 2]; r1w3 = supW[(64 + tid) * 4 + 3];
        }
        unsigned kw0 = keepW[0], kw1 = keepW[1], kw2 = keepW[2], kw3 = keepW[3];
        #pragma unroll
        for (int i = 0; i < PRE_NMS - 1; ++i) {
            unsigned kword = (i < 32) ? kw0 : (i < 64) ? kw1 : (i < 96) ? kw2 : kw3;
            if ((kword >> (i & 31)) & 1u) {   // uniform across the wave
                unsigned s0, s1, s2, s3;
                if (i < 64) {
                    s0 = __shfl(r0w0, i, 64); s1 = __shfl(r0w1, i, 64);
                    s2 = __shfl(r0w2, i, 64); s3 = __shfl(r0w3, i, 64);
                } else {
                    s0 = __shfl(r1w0, i - 64, 64); s1 = __shfl(r1w1, i - 64, 64);
                    s2 = __shfl(r1w2, i - 64, 64); s3 = __shfl(r1w3, i - 64, 64);
                }
                kw0 &= ~s0; kw1 &= ~s1; kw2 &= ~s2; kw3 &= ~s3;
            }
        }
        if (tid == 0) { keepW[0] = kw0; keepW[1] = kw1; keepW[2] = kw2; keepW[3] = kw3; }
    }
    __syncthreads();

    if (tid < PRE_NMS) osrc[tid] = -1;
    __syncthreads();
    if (tid < PRE_NMS) {
        unsigned k0 = keepW[0], k1 = keepW[1], k2 = keepW[2], k3 = keepW[3];
        int w = tid >> 5, bit = tid & 31;
        unsigned kword = (w == 0) ? k0 : (w == 1) ? k1 : (w == 2) ? k2 : k3;
        if ((kword >> bit) & 1u) {
            int pos = __popc(kword & ((1u << bit) - 1u));
            if (w > 0) pos += __popc(k0);
            if (w > 1) pos += __popc(k1);
            if (w > 2) pos += __popc(k2);
            osrc[pos] = tid;
        }
    }
    __syncthreads();

    float* ob = out + (size_t)b * (PRE_NMS * 5);
    if (tid < PRE_NMS) {
        int j = osrc[tid];
        float r0 = 0.f, r1 = 0.f, r2 = 0.f, r3 = 0.f, r4 = 0.f;
        if (j >= 0) { r0 = bx1[j]; r1 = by1[j]; r2 = bx2[j]; r3 = by2[j]; r4 = bsc[j]; }
        ob[tid * 5 + 0] = r0;
        ob[tid * 5 + 1] = r1;
        ob[tid * 5 + 2] = r2;
        ob[tid * 5 + 3] = r3;
        ob[tid * 5 + 4] = r4;
    }
}

// ----------------------------------------------------------------- launch ---
extern "C" void kernel_launch(void* const* d_in, const int* in_sizes, int n_in,
                              void* d_out, int out_size, void* d_ws, size_t ws_size,
                              hipStream_t stream) {
    const float* score = (const float*)d_in[0];
    const float* delta = (const float*)d_in[1];
    const float* img   = (const float*)d_in[2];
    float* out = (float*)d_out;

    int B = in_sizes[0] / (2 * NA * HWSZ);   // 32 for the reference shapes

    // ws layout: [cand: B*CAP u64][tArr: B u32][cntArr: B u32][mask: NANC u8]
    unsigned long long* cand = (unsigned long long*)d_ws;
    unsigned int* tArr   = (unsigned int*)((char*)d_ws + (size_t)B * CAP * 8);
    unsigned int* cntArr = tArr + B;
    unsigned char* mask  = (unsigned char*)(cntArr + B);

    k_mask<<<(NANC + 255) / 256, 256, 0, stream>>>(delta, img, mask);
    k_select<<<B, 1024, 0, stream>>>(score, mask, tArr, cntArr);
    dim3 gc((NANC4 + 1023) / 1024, B);
    k_compact<<<gc, 256, 0, stream>>>(score, mask, tArr, cntArr, cand);
    k_final<<<B, 1024, 0, stream>>>(cand, cntArr, delta, img, out);
}

// Round 4
// 153.024 us; speedup vs baseline: 1.0835x; 1.0835x over previous
//
#include <hip/hip_runtime.h>
#include <math.h>

// Problem constants (reference setup_inputs: B=32, H=80, W=120, A=9)
#define NA     9
#define HH     80
#define WWID   120
#define HWSZ   (HH * WWID)        // 9600
#define NANC   (HWSZ * NA)        // 86400 anchors per image
#define NANC4  (NANC / 4)         // 21600 float4 groups
#define PRE_NMS 100
#define NMS_THRESH 0.3f
#define MIN_SIZE 8.0f
#define STRIDE_F 16.0f
#define NBIN   4096               // 12-bit histogram of ordered-f32
#define CAP    2048               // per-batch candidate cap (expected ~183)
#define NCH    22                 // chunks of 1024 float4-groups (22*1024 >= 21600)

// Anchor geometry: all 9 anchors share center (8,8); widths/heights exact
// (verified against _generate_anchors(16,(0.5,1,2),(8,16,32))).
__constant__ float c_aw[NA] = {184.f, 368.f, 736.f, 128.f, 256.f, 512.f,  88.f, 176.f, 352.f};
__constant__ float c_ah[NA] = { 96.f, 192.f, 384.f, 128.f, 256.f, 512.f, 176.f, 352.f, 704.f};

// ---------------------------------------------------------------- decode ----
__device__ inline void decode_box(int n, float4 d, float imgW, float imgH,
                                  float& x1, float& y1, float& x2, float& y2) {
    int a = n % NA;
    int s = n / NA;
    int yy = s / WWID;
    int xx = s - yy * WWID;
    float aw = c_aw[a], ah = c_ah[a];
    float acx = 8.0f + STRIDE_F * (float)xx;
    float acy = 8.0f + STRIDE_F * (float)yy;
    float pcx = d.x * aw + acx;
    float pcy = d.y * ah + acy;
    float pw  = expf(d.z) * aw;
    float ph  = expf(d.w) * ah;
    x1 = pcx - 0.5f * pw;
    y1 = pcy - 0.5f * ph;
    x2 = pcx + 0.5f * pw;
    y2 = pcy + 0.5f * ph;
    float mx = imgW - 1.0f, my = imgH - 1.0f;
    x1 = fminf(fmaxf(x1, 0.0f), mx);
    x2 = fminf(fmaxf(x2, 0.0f), mx);
    y1 = fminf(fmaxf(y1, 0.0f), my);
    y2 = fminf(fmaxf(y2, 0.0f), my);
}

// order-preserving uint mapping (monotonic for all floats incl +-inf)
__device__ inline unsigned int f32_ord(float v) {
    unsigned int u = __float_as_uint(v);
    return (u & 0x80000000u) ? ~u : (u | 0x80000000u);
}
__device__ inline float ord_f32(unsigned int ov) {
    unsigned int u = (ov & 0x80000000u) ? (ov ^ 0x80000000u) : ~ov;
    return __uint_as_float(u);
}

// ------------------------- K0: batch-0 size mask + zero global histogram ----
// mask stored in score-memory order m = a*HWSZ + s so later reads coalesce.
__global__ void k_mask(const float* __restrict__ delta,
                       const float* __restrict__ img,
                       unsigned char* __restrict__ mask,
                       unsigned int* __restrict__ ghist, int nhist) {
    int gid = blockIdx.x * blockDim.x + threadIdx.x;
    for (int i = gid; i < nhist; i += gridDim.x * blockDim.x) ghist[i] = 0u;
    if (gid >= NANC) return;
    float4 d = reinterpret_cast<const float4*>(delta)[gid];  // batch 0, contiguous
    float imgH = img[0], imgW = img[1];
    float x1, y1, x2, y2;
    decode_box(gid, d, imgW, imgH, x1, y1, x2, y2);
    float ws = x2 - x1 + 1.0f;
    float hs = y2 - y1 + 1.0f;
    int a = gid % NA;
    int s = gid / NA;
    mask[a * HWSZ + s] = (ws >= MIN_SIZE && hs >= MIN_SIZE) ? 1 : 0;
}

// ------------- K1: per-(chunk,batch) LDS histogram -> global accumulate -----
__global__ __launch_bounds__(256)
void k_hist(const float* __restrict__ score,
            const unsigned char* __restrict__ mask,
            unsigned int* __restrict__ ghist) {
    __shared__ unsigned int lh[NBIN];
    int chunk = blockIdx.x, b = blockIdx.y, tid = threadIdx.x;
    for (int i = tid; i < NBIN; i += 256) lh[i] = 0u;
    __syncthreads();

    const float4* fg = reinterpret_cast<const float4*>(
        score + (size_t)b * (2 * NA * HWSZ) + (size_t)NA * HWSZ);
    const uchar4* mk = reinterpret_cast<const uchar4*>(mask);
    #pragma unroll
    for (int it = 0; it < 4; ++it) {
        int q = chunk * 1024 + it * 256 + tid;
        if (q < NANC4) {
            float4 v = fg[q];
            uchar4 m = mk[q];
            float a0 = m.x ? v.x : -INFINITY;
            float a1 = m.y ? v.y : -INFINITY;
            float a2 = m.z ? v.z : -INFINITY;
            float a3 = m.w ? v.w : -INFINITY;
            atomicAdd(&lh[f32_ord(a0) >> 20], 1u);
            atomicAdd(&lh[f32_ord(a1) >> 20], 1u);
            atomicAdd(&lh[f32_ord(a2) >> 20], 1u);
            atomicAdd(&lh[f32_ord(a3) >> 20], 1u);
        }
    }
    __syncthreads();
    unsigned int* gh = ghist + (size_t)b * NBIN;
    for (int i = tid; i < NBIN; i += 256) {
        unsigned c = lh[i];
        if (c) atomicAdd(&gh[i], c);   // zero-skip: ~200-400 nonzero bins/block
    }
}

// ------------- K2: per-batch suffix-scan of histogram -> threshold bin T ----
// T = max bin with count(bins >= T) >= 100  => global top-100 all in bins >= T.
__global__ __launch_bounds__(256)
void k_thresh(const unsigned int* __restrict__ ghist,
              unsigned int* __restrict__ tArr,
              unsigned int* __restrict__ cntArr) {
    __shared__ unsigned int part[256];
    __shared__ int best;
    int b = blockIdx.x, tid = threadIdx.x;
    if (tid == 0) best = 0;
    unsigned g[16];
    unsigned s = 0;
    const unsigned int* h = ghist + (size_t)b * NBIN + tid * 16;
    #pragma unroll
    for (int j = 0; j < 16; ++j) { g[j] = h[j]; s += g[j]; }
    part[tid] = s;
    __syncthreads();
    for (int off = 1; off < 256; off <<= 1) {     // inclusive suffix scan
        unsigned v = (tid + off < 256) ? part[tid + off] : 0u;
        __syncthreads();
        part[tid] += v;
        __syncthreads();
    }
    unsigned cum = (tid + 1 < 256) ? part[tid + 1] : 0u;  // exclusive suffix
    int loc = -1;
    #pragma unroll
    for (int j = 15; j >= 0; --j) {               // largest in-thread bin first
        cum += g[j];
        if (cum >= PRE_NMS) { loc = tid * 16 + j; break; }
    }
    if (loc >= 0) atomicMax(&best, loc);
    __syncthreads();
    if (tid == 0) { tArr[b] = (unsigned)best; cntArr[b] = 0u; }
}

// ---------------- K3: compact all elements with bin >= T into candidates ----
__global__ __launch_bounds__(256)
void k_compact(const float* __restrict__ score,
               const unsigned char* __restrict__ mask,
               const unsigned int* __restrict__ tArr,
               unsigned int* __restrict__ cntArr,
               unsigned long long* __restrict__ cand) {
    int chunk = blockIdx.x, b = blockIdx.y, tid = threadIdx.x;
    unsigned T = tArr[b];
    const float4* fg = reinterpret_cast<const float4*>(
        score + (size_t)b * (2 * NA * HWSZ) + (size_t)NA * HWSZ);
    const uchar4* mk = reinterpret_cast<const uchar4*>(mask);
    #pragma unroll
    for (int it = 0; it < 4; ++it) {
        int q = chunk * 1024 + it * 256 + tid;
        if (q >= NANC4) continue;
        float4 v = fg[q];
        uchar4 m = mk[q];
        float av[4] = { m.x ? v.x : -INFINITY, m.y ? v.y : -INFINITY,
                        m.z ? v.z : -INFINITY, m.w ? v.w : -INFINITY };
        #pragma unroll
        for (int c = 0; c < 4; ++c) {
            unsigned ov = f32_ord(av[c]);
            if ((ov >> 20) >= T) {
                int mfull = 4 * q + c;               // memory order a*HWSZ + s
                int a = mfull / HWSZ;
                int s = mfull - a * HWSZ;
                unsigned n = (unsigned)(s * NA + a);  // anchor order (top_k index)
                unsigned slot = atomicAdd(&cntArr[b], 1u);
                if (slot < CAP)
                    cand[(size_t)b * CAP + slot] =
                        ((unsigned long long)ov << 32) |
                        (unsigned long long)(0xFFFFFFFFu - n);  // low idx wins ties
            }
        }
    }
}

// generic in-LDS bitonic sort, descending, S = power of 2 (block-uniform)
__device__ inline void bitonic_desc(unsigned long long* sh, int S, int nthr) {
    for (int k = 2; k <= S; k <<= 1) {
        for (int j = k >> 1; j > 0; j >>= 1) {
            for (int i = threadIdx.x; i < S; i += nthr) {
                int ix = i ^ j;
                if (ix > i) {
                    unsigned long long va = sh[i], vb = sh[ix];
                    bool up = ((i & k) == 0);
                    bool sw = up ? (va < vb) : (va > vb);
                    if (sw) { sh[i] = vb; sh[ix] = va; }
                }
            }
            __syncthreads();
        }
    }
}

// --------- K4: per-batch sort candidates, decode top-100, NMS, write -------
__global__ __launch_bounds__(512)
void k_final(const unsigned long long* __restrict__ cand,
             const unsigned int* __restrict__ cntArr,
             const float* __restrict__ delta,
             const float* __restrict__ img,
             float* __restrict__ out) {
    __shared__ unsigned long long sh[CAP];
    __shared__ float bx1[PRE_NMS], by1[PRE_NMS], bx2[PRE_NMS], by2[PRE_NMS];
    __shared__ float bsc[PRE_NMS], barea[PRE_NMS];
    __shared__ unsigned int supW[PRE_NMS * 4];   // suppress bit-matrix rows
    __shared__ unsigned int keepW[4];
    __shared__ int osrc[PRE_NMS];

    int b = blockIdx.x, tid = threadIdx.x;
    int nc = min((int)cntArr[b], CAP);
    int S = 128;
    while (S < nc) S <<= 1;

    for (int l = tid; l < S; l += 512)
        sh[l] = (l < nc) ? cand[(size_t)b * CAP + l] : 0ull;
    if (tid < 4) keepW[tid] = 0u;
    if (tid < PRE_NMS * 4) supW[tid] = 0u;
    __syncthreads();

    bitonic_desc(sh, S, 512);   // ends with __syncthreads

    float imgH = img[0], imgW = img[1];
    if (tid < PRE_NMS) {
        unsigned long long key = sh[tid];
        float x1 = 0.f, y1 = 0.f, x2 = 0.f, y2 = 0.f, v = -INFINITY, ar = 1.f;
        if (key != 0ull) {   // real candidate (pad keys are exactly 0)
            unsigned n = 0xFFFFFFFFu - (unsigned)(key & 0xFFFFFFFFu);
            v = ord_f32((unsigned)(key >> 32));
            // delta.reshape(B,-1,4): row n = flat elems [4n..4n+3] (contiguous)
            float4 d = reinterpret_cast<const float4*>(
                delta + (size_t)b * (4 * NANC))[n];
            decode_box((int)n, d, imgW, imgH, x1, y1, x2, y2);
            ar = (x2 - x1 + 1.0f) * (y2 - y1 + 1.0f);
        }
        bx1[tid] = x1; by1[tid] = y1; bx2[tid] = x2; by2[tid] = y2;
        bsc[tid] = v;  barea[tid] = ar;
        if (key != 0ull && isfinite(v))
            atomicOr(&keepW[tid >> 5], 1u << (tid & 31));
    }
    __syncthreads();

    // 100x100 suppress matrix: bit j of row i set iff j>i and IoU>thresh
    for (int p = tid; p < PRE_NMS * PRE_NMS; p += 512) {
        int i = p / PRE_NMS;
        int j = p - i * PRE_NMS;
        if (j > i) {
            float ix1 = fmaxf(bx1[i], bx1[j]);
            float iy1 = fmaxf(by1[i], by1[j]);
            float ix2 = fminf(bx2[i], bx2[j]);
            float iy2 = fminf(by2[i], by2[j]);
            float iw = fmaxf(ix2 - ix1 + 1.0f, 0.0f);
            float ih = fmaxf(iy2 - iy1 + 1.0f, 0.0f);
            float inter = iw * ih;
            float iou = inter / (barea[i] + barea[j] - inter);
            if (iou > NMS_THRESH)
                atomicOr(&supW[i * 4 + (j >> 5)], 1u << (j & 31));
        }
    }
    __syncthreads();

    // greedy pass entirely in wave-0 registers (no barriers)
    if (tid < 64) {
        unsigned r0w0 = supW[tid * 4 + 0], r0w1 = supW[tid * 4 + 1];
        unsigned r0w2 = supW[tid * 4 + 2], r0w3 = supW[tid * 4 + 3];
        unsigned r1w0 = 0, r1w1 = 0, r1w2 = 0, r1w3 = 0;
        if (tid < PRE_NMS - 64) {
            r1w0 = supW[(64 + tid) * 4 + 0]; r1w1 = supW[(64 + tid) * 4 + 1];
            r1w2 = supW[(64 + tid) * 4 + 2]; r1w3 = supW[(64 + tid) * 4 + 3];
        }
        unsigned kw0 = keepW[0], kw1 = keepW[1], kw2 = keepW[2], kw3 = keepW[3];
        #pragma unroll
        for (int i = 0; i < PRE_NMS - 1; ++i) {
            unsigned kword = (i < 32) ? kw0 : (i < 64) ? kw1 : (i < 96) ? kw2 : kw3;
            if ((kword >> (i & 31)) & 1u) {   // uniform across the wave
                unsigned s0, s1, s2, s3;
                if (i < 64) {
                    s0 = __shfl(r0w0, i, 64); s1 = __shfl(r0w1, i, 64);
                    s2 = __shfl(r0w2, i, 64); s3 = __shfl(r0w3, i, 64);
                } else {
                    s0 = __shfl(r1w0, i - 64, 64); s1 = __shfl(r1w1, i - 64, 64);
                    s2 = __shfl(r1w2, i - 64, 64); s3 = __shfl(r1w3, i - 64, 64);
                }
                kw0 &= ~s0; kw1 &= ~s1; kw2 &= ~s2; kw3 &= ~s3;
            }
        }
        if (tid == 0) { keepW[0] = kw0; keepW[1] = kw1; keepW[2] = kw2; keepW[3] = kw3; }
    }
    __syncthreads();

    if (tid < PRE_NMS) osrc[tid] = -1;
    __syncthreads();
    if (tid < PRE_NMS) {
        unsigned k0 = keepW[0], k1 = keepW[1], k2 = keepW[2], k3 = keepW[3];
        int w = tid >> 5, bit = tid & 31;
        unsigned kword = (w == 0) ? k0 : (w == 1) ? k1 : (w == 2) ? k2 : k3;
        if ((kword >> bit) & 1u) {
            int pos = __popc(kword & ((1u << bit) - 1u));
            if (w > 0) pos += __popc(k0);
            if (w > 1) pos += __popc(k1);
            if (w > 2) pos += __popc(k2);
            osrc[pos] = tid;
        }
    }
    __syncthreads();

    float* ob = out + (size_t)b * (PRE_NMS * 5);
    if (tid < PRE_NMS) {
        int j = osrc[tid];
        float r0 = 0.f, r1 = 0.f, r2 = 0.f, r3 = 0.f, r4 = 0.f;
        if (j >= 0) { r0 = bx1[j]; r1 = by1[j]; r2 = bx2[j]; r3 = by2[j]; r4 = bsc[j]; }
        ob[tid * 5 + 0] = r0;
        ob[tid * 5 + 1] = r1;
        ob[tid * 5 + 2] = r2;
        ob[tid * 5 + 3] = r3;
        ob[tid * 5 + 4] = r4;
    }
}

// ----------------------------------------------------------------- launch ---
extern "C" void kernel_launch(void* const* d_in, const int* in_sizes, int n_in,
                              void* d_out, int out_size, void* d_ws, size_t ws_size,
                              hipStream_t stream) {
    const float* score = (const float*)d_in[0];
    const float* delta = (const float*)d_in[1];
    const float* img   = (const float*)d_in[2];
    float* out = (float*)d_out;

    int B = in_sizes[0] / (2 * NA * HWSZ);   // 32 for the reference shapes

    // ws layout: [cand: B*CAP u64][ghist: B*NBIN u32][tArr: B u32][cntArr: B u32][mask: NANC u8]
    unsigned long long* cand = (unsigned long long*)d_ws;
    unsigned int* ghist  = (unsigned int*)((char*)d_ws + (size_t)B * CAP * 8);
    unsigned int* tArr   = ghist + (size_t)B * NBIN;
    unsigned int* cntArr = tArr + B;
    unsigned char* mask  = (unsigned char*)(cntArr + B);

    k_mask<<<(NANC + 255) / 256, 256, 0, stream>>>(delta, img, mask, ghist, B * NBIN);
    dim3 gh(NCH, B);
    k_hist<<<gh, 256, 0, stream>>>(score, mask, ghist);
    k_thresh<<<B, 256, 0, stream>>>(ghist, tArr, cntArr);
    k_compact<<<gh, 256, 0, stream>>>(score, mask, tArr, cntArr, cand);
    k_final<<<B, 512, 0, stream>>>(cand, cntArr, delta, img, out);
}